// Round 4
// baseline (476.006 us; speedup 1.0000x reference)
//
#include <hip/hip_runtime.h>
#include <hip/hip_bf16.h>

// LSTM encoder: B=4096, L=512, M=H=17.
// Strategy: 256 blocks x 16 batch, FOUR waves/block (one per SIMD).
// gates(80x16) = W'(80x64) . [x|h](64x16) via mfma_f32_16x16x32_bf16,
// bias as C operand. Weight rows interleaved row=4*j+type so each lane's 4 acc
// regs are (i,f,g,o) for one j -> lane-local epilogue, c in a single register.
//
// R4 changes:
//  - TPB 320 -> 256. The 5-wave config put 2 waves on one SIMD; their issue
//    serialized (~200cy epilogue issue each) and the per-step barrier pinned
//    the whole block to that straggler pair, every one of 544 phases.
//  - The 5th N-tile (j=16, W rows 64..79) is computed REDUNDANTLY by every
//    wave: +1 MFMA and +1 epilogue set (real only in q==0 lanes; padded
//    weight rows are zero so other lanes compute benign zeros). Only q==0
//    lanes write h_s[bb][16] (same value from all 4 waves - benign).
//  - All set-A lanes are real (j=0..15): active/clamp machinery removed.
//  - __launch_bounds__(256,1): 1 wave/SIMD anyway; lets hist+hist4 (128
//    VGPRs) stay in registers without spill.

namespace {
constexpr int B_TOT = 4096;
constexpr int L_SEQ = 512;
constexpr int NF    = 17;                    // features == hidden
constexpr int BS    = 16;                    // batch per block
constexpr int TPB   = 256;                   // 4 waves, one per SIMD
constexpr int TC    = 16;                    // timesteps per staged chunk
constexpr int NCHUNK = L_SEQ / TC;           // 32
constexpr int KPAD  = 24;                    // k-pad for x_s/h_s rows (quads 0..2)
constexpr int F4_PER_ROW   = TC * NF / 4;    // 68 float4 per batch-row chunk
constexpr int F4_PER_CHUNK = BS * F4_PER_ROW;// 1088
constexpr int PF_MAX = (F4_PER_CHUNK + TPB - 1) / TPB;  // 5

constexpr int OUT_H = B_TOT * L_SEQ * NF;    // 35,651,584
constexpr int OUT_C = OUT_H + B_TOT * NF;
constexpr int OUT_X = OUT_C + B_TOT * NF;
}

typedef __attribute__((ext_vector_type(8))) short bf16x8;
typedef __attribute__((ext_vector_type(4))) float f32x4;

__device__ __forceinline__ unsigned short f2bf(float f) {
  union { float f; unsigned int u; } v; v.f = f;
  unsigned int r = v.u + 0x7fff + ((v.u >> 16) & 1);   // RNE
  return (unsigned short)(r >> 16);
}
// Single-instruction f32->bf16 (RNE).
__device__ __forceinline__ unsigned short h2bf(float f) {
  unsigned int r;
  asm("v_cvt_pk_bf16_f32 %0, %1, %2" : "=v"(r) : "v"(f), "v"(f));
  return (unsigned short)r;
}
__device__ __forceinline__ float sigm(float x) {
  return __builtin_amdgcn_rcpf(1.f + __expf(-x));
}
__device__ __forceinline__ float tanh_fast(float x) {
  float e = __expf(2.f * x);                 // exp overflow -> inf -> rcp -> 0: safe
  return 1.f - 2.f * __builtin_amdgcn_rcpf(e + 1.f);
}

// Forced-global stores: vmcnt-only, fire-and-forget, exec-masked under divergence.
__device__ __forceinline__ void gstore1(float* p, float v) {
  asm volatile("global_store_dword %0, %1, off" :: "v"(p), "v"(v));
}
__device__ __forceinline__ void gstore4(float* p, f32x4 v) {
  asm volatile("global_store_dwordx4 %0, %1, off" :: "v"(p), "v"(v));
}

// LDS-only barrier: order h_s/x_s handoff without draining vmem queues.
__device__ __forceinline__ void block_sync_lds() {
  asm volatile("s_waitcnt lgkmcnt(0)" ::: "memory");
  __builtin_amdgcn_s_barrier();
  asm volatile("" ::: "memory");
}

__global__ void __launch_bounds__(TPB, 1) lstm_kernel(
    const float* __restrict__ x, const float* __restrict__ W_ih,
    const float* __restrict__ W_hh, const float* __restrict__ b_ih,
    const float* __restrict__ b_hh, float* __restrict__ out)
{
  __shared__ __align__(16) unsigned short x_s[2][TC][BS][KPAD]; // bf16 bits, 24 KiB
  __shared__ __align__(16) unsigned short h_s[2][BS][KPAD];     // bf16 bits
  __shared__ __align__(16) unsigned short w0_s[80][32];         // W_ih', interleaved rows
  __shared__ __align__(16) unsigned short w1_s[80][32];         // W_hh'
  __shared__ __align__(16) float bias_s[80];
  __shared__ __align__(16) unsigned short zero16[8];            // zero frag for quad 3

  const int tid  = threadIdx.x;
  const int lane = tid & 63;
  const int T    = tid >> 6;        // wave id == own N-tile id (0..3)
  const int bb   = lane & 15;       // batch within block (B-frag n, C col)
  const int q    = lane >> 4;       // quad (k-octet for A/B frags, row-quad for C)
  const int b0   = blockIdx.x * BS;

  // ---- prefetch chunk 0 into registers (issue ASAP)
  f32x4 pf[PF_MAX];
  #pragma unroll
  for (int i = 0; i < PF_MAX; ++i) {
    int u = tid + TPB * i;
    if (u < F4_PER_CHUNK) {
      int row = u / F4_PER_ROW, off = u % F4_PER_ROW;
      pf[i] = *(const f32x4*)(x + ((b0 + row) * L_SEQ) * NF + off * 4);
    }
  }

  // ---- zero LDS (x_s pads persist; h0=c0=0)
  {
    unsigned int* p = (unsigned int*)&x_s[0][0][0][0];
    for (int u = tid; u < (int)(sizeof(x_s) / 4); u += TPB) p[u] = 0;
    unsigned int* ph = (unsigned int*)&h_s[0][0][0];
    for (int u = tid; u < (int)(sizeof(h_s) / 4); u += TPB) ph[u] = 0;
    if (tid < 4) ((unsigned int*)zero16)[tid] = 0;
  }
  // ---- build interleaved weight tiles + fused bias
  for (int u = tid; u < 80 * 32; u += TPB) {
    int r = u >> 5, k = u & 31;
    unsigned short v0 = 0, v1 = 0;
    int j = -1, ty = 0;
    if (r < 64)      { j = r >> 2; ty = r & 3; }
    else if (r < 68) { j = 16;     ty = r - 64; }
    if (j >= 0 && k < NF) {
      int g = ty * NF + j;          // torch gate order i,f,g,o
      v0 = f2bf(W_ih[g * NF + k]);
      v1 = f2bf(W_hh[g * NF + k]);
    }
    w0_s[r][k] = v0; w1_s[r][k] = v1;
  }
  for (int u = tid; u < 80; u += TPB) {
    float bv = 0.f; int j = -1, ty = 0;
    if (u < 64)      { j = u >> 2; ty = u & 3; }
    else if (u < 68) { j = 16;     ty = u - 64; }
    if (j >= 0) { int g = ty * NF + j; bv = b_ih[g] + b_hh[g]; }
    bias_s[u] = bv;
  }
  __syncthreads();   // zero-init & weights visible before staging/frag reads

  // ---- stage helper: write pf (chunk cn) to x_s[cn&1] + passthrough x copy
  auto stage = [&](int cn) {
    #pragma unroll
    for (int i = 0; i < PF_MAX; ++i) {
      int u = tid + TPB * i;
      if (u < F4_PER_CHUNK) {
        int row = u / F4_PER_ROW, off = u % F4_PER_ROW;
        int gidx = ((b0 + row) * L_SEQ + cn * TC) * NF + off * 4;
        gstore4(out + OUT_X + gidx, pf[i]);
        int p = off * 4, tl = p / NF, m = p - tl * NF;
        #pragma unroll
        for (int e = 0; e < 4; ++e) {
          x_s[cn & 1][tl][row][m] = f2bf(pf[i][e]);
          if (++m == NF) { m = 0; ++tl; }
        }
      }
    }
  };
  auto prefetch = [&](int cn) {
    #pragma unroll
    for (int i = 0; i < PF_MAX; ++i) {
      int u = tid + TPB * i;
      if (u < F4_PER_CHUNK) {
        int row = u / F4_PER_ROW, off = u % F4_PER_ROW;
        pf[i] = *(const f32x4*)(x + ((b0 + row) * L_SEQ + cn * TC) * NF + off * 4);
      }
    }
  };

  stage(0);        // writes buf 0; visible after chunk-top barrier
  prefetch(1);

  // ---- per-wave constant fragments: own tile + redundant tile 4 (j=16)
  const bf16x8 a0  = *(const bf16x8*)&w0_s[16 * T + bb][q * 8];
  const bf16x8 a1  = *(const bf16x8*)&w1_s[16 * T + bb][q * 8];
  const f32x4 bias4  = *(const f32x4*)&bias_s[16 * T + q * 4];
  const bf16x8 a40 = *(const bf16x8*)&w0_s[64 + bb][q * 8];
  const bf16x8 a41 = *(const bf16x8*)&w1_s[64 + bb][q * 8];
  const f32x4 bias44 = *(const f32x4*)&bias_s[64 + q * 4];

  const int j = 4 * T + q;                       // 0..15: all lanes real
  const bool q0   = (q == 0);                    // j=16 real lanes
  const bool w0q0 = (T == 0) && q0;              // unique writer for j=16 output

  // All LDS pointers as distinct named scalars (no runtime-indexed arrays).
  const unsigned short* const xbase0 = (q == 3) ? zero16 : &x_s[0][0][bb][q * 8];
  const unsigned short* const xbase1 = (q == 3) ? zero16 : &x_s[1][0][bb][q * 8];
  const int xstep = (q == 3) ? 0 : BS * KPAD;    // ushorts per timestep
  const unsigned short* const hr0 = (q == 3) ? zero16 : &h_s[0][bb][q * 8]; // read, even t
  const unsigned short* const hr1 = (q == 3) ? zero16 : &h_s[1][bb][q * 8]; // read, odd t
  unsigned short* const hwA0 = &h_s[1][bb][j];   // own-j write after even t
  unsigned short* const hwA1 = &h_s[0][bb][j];   // own-j write after odd t
  unsigned short* const hw40 = &h_s[1][bb][16];  // j=16 write after even t (q0 only)
  unsigned short* const hw41 = &h_s[0][bb][16];  // j=16 write after odd t (q0 only)

  float cA = 0.f, hA = 0.f;                      // own-j state
  float c4 = 0.f, h4 = 0.f;                      // j=16 state (redundant per wave)
  float* outpA = out + (b0 + bb) * L_SEQ * NF + j;
  float* outp4 = out + (b0 + bb) * L_SEQ * NF + 16;

  // ---- main recurrence
  for (int c = 0; c < NCHUNK; ++c) {
    block_sync_lds();          // staged x_s[c&1] visible to all before burst

    // Burst: x-projection for all TC steps (own tile + tile 4) into registers.
    const unsigned short* xq = (c & 1) ? xbase1 : xbase0;
    f32x4 hist[TC], hist4[TC];
    #pragma unroll
    for (int tt = 0; tt < TC; ++tt) {
      bf16x8 bx = *(const bf16x8*)(xq + tt * xstep);
      hist [tt] = __builtin_amdgcn_mfma_f32_16x16x32_bf16(a0,  bx, bias4,  0, 0, 0);
      hist4[tt] = __builtin_amdgcn_mfma_f32_16x16x32_bf16(a40, bx, bias44, 0, 0, 0);
    }

    // Steps: barrier -> ds_read h -> 2 MFMA -> 2 epilogues -> ds_write h.
    #pragma unroll
    for (int tt = 0; tt < TC; tt += 2) {
      // even step t: read h_s[0], write h_s[1]
      block_sync_lds();
      {
        bf16x8 bh = *(const bf16x8*)hr0;
        f32x4 accA = __builtin_amdgcn_mfma_f32_16x16x32_bf16(a1,  bh, hist [tt], 0, 0, 0);
        f32x4 acc4 = __builtin_amdgcn_mfma_f32_16x16x32_bf16(a41, bh, hist4[tt], 0, 0, 0);
        // own j (all lanes)
        {
          float gi = sigm(accA[0]), gf = sigm(accA[1]);
          float gg = tanh_fast(accA[2]), go = sigm(accA[3]);
          cA = gf * cA + gi * gg;
          hA = go * tanh_fast(cA);
          *hwA0 = h2bf(hA);
          gstore1(outpA, hA); outpA += NF;
        }
        // j=16 (real in q0 lanes; others benign zeros)
        {
          float gi = sigm(acc4[0]), gf = sigm(acc4[1]);
          float gg = tanh_fast(acc4[2]), go = sigm(acc4[3]);
          c4 = gf * c4 + gi * gg;
          h4 = go * tanh_fast(c4);
          if (q0)   *hw40 = h2bf(h4);
          if (w0q0) gstore1(outp4, h4);
          outp4 += NF;
        }
      }
      // odd step t+1: read h_s[1], write h_s[0]
      block_sync_lds();
      {
        bf16x8 bh = *(const bf16x8*)hr1;
        f32x4 accA = __builtin_amdgcn_mfma_f32_16x16x32_bf16(a1,  bh, hist [tt + 1], 0, 0, 0);
        f32x4 acc4 = __builtin_amdgcn_mfma_f32_16x16x32_bf16(a41, bh, hist4[tt + 1], 0, 0, 0);
        {
          float gi = sigm(accA[0]), gf = sigm(accA[1]);
          float gg = tanh_fast(accA[2]), go = sigm(accA[3]);
          cA = gf * cA + gi * gg;
          hA = go * tanh_fast(cA);
          *hwA1 = h2bf(hA);
          gstore1(outpA, hA); outpA += NF;
        }
        {
          float gi = sigm(acc4[0]), gf = sigm(acc4[1]);
          float gg = tanh_fast(acc4[2]), go = sigm(acc4[3]);
          c4 = gf * c4 + gi * gg;
          h4 = go * tanh_fast(c4);
          if (q0)   *hw41 = h2bf(h4);
          if (w0q0) gstore1(outp4, h4);
          outp4 += NF;
        }
      }
    }

    if (c + 1 < NCHUNK) {
      stage(c + 1);                              // other x buffer: no race with burst/steps
      if (c + 2 < NCHUNK) prefetch(c + 2);
    }
  }

  // ---- final states
  gstore1(out + OUT_H + (b0 + bb) * NF + j, hA);
  gstore1(out + OUT_C + (b0 + bb) * NF + j, cA);
  if (w0q0) {
    gstore1(out + OUT_H + (b0 + bb) * NF + 16, h4);
    gstore1(out + OUT_C + (b0 + bb) * NF + 16, c4);
  }
}

extern "C" void kernel_launch(void* const* d_in, const int* in_sizes, int n_in,
                              void* d_out, int out_size, void* d_ws, size_t ws_size,
                              hipStream_t stream) {
  (void)in_sizes; (void)n_in; (void)out_size; (void)d_ws; (void)ws_size;
  const float* x    = (const float*)d_in[0];
  const float* W_ih = (const float*)d_in[1];
  const float* W_hh = (const float*)d_in[2];
  const float* b_ih = (const float*)d_in[3];
  const float* b_hh = (const float*)d_in[4];
  float* out = (float*)d_out;
  hipLaunchKernelGGL(lstm_kernel, dim3(B_TOT / BS), dim3(TPB), 0, stream,
                     x, W_ih, W_hh, b_ih, b_hh, out);
}